// Round 5
// baseline (449.979 us; speedup 1.0000x reference)
//
#include <hip/hip_runtime.h>

#define BATCH 256
#define SEQ_T 512
#define CIN   6
#define RES   256
// h stored as 16 chunks of 16 floats; chunk stride padded to 20 dwords (80 B,
// 16B-aligned). Read inst j: 16 distinct addresses (one per sub), each
// broadcast to 4 lanes; bases 20s%32 tile banks 2-way -> free (measured 0).
#define NCH     16
#define CSTRIDE 20
#define HBUF    (NCH * CSTRIDE)   // 320 dwords per buffer

typedef float f32x2 __attribute__((ext_vector_type(2)));

// Packed fp32 FMA (VOP3P, full-rate per R3 measurement).
__device__ __forceinline__ f32x2 pk_fma(f32x2 a, f32x2 b, f32x2 c) {
    f32x2 d;
    asm("v_pk_fma_f32 %0, %1, %2, %3" : "=v"(d) : "v"(a), "v"(b), "v"(c));
    return d;
}

// v + dpp<CTRL>(v)
template <int CTRL>
__device__ __forceinline__ float dpp_add(float v) {
    union { float f; int i; } u;
    u.f = v;
    u.i = __builtin_amdgcn_mov_dpp(u.i, CTRL, 0xF, 0xF, true);
    return v + u.f;
}

// keep + dpp<CTRL>(give)  (butterfly stage with index splitting)
template <int CTRL>
__device__ __forceinline__ float dpp_xadd(float keep, float give) {
    union { float f; int i; } u;
    u.f = give;
    u.i = __builtin_amdgcn_mov_dpp(u.i, CTRL, 0xF, 0xF, true);
    return keep + u.f;
}

// One workgroup (512 threads = 8 waves) per batch row.
// KEY CHANGE vs R4: the per-lane W slice (128 floats = 64 VGPR pairs) is
// PINNED into VGPRs via opaque asm after the prologue load. Rounds R0-R4 all
// reported VGPR_Count (44/48/48/84) smaller than the declared W slice -> the
// allocator was rematerializing W loads inside the time loop, re-streaming
// 256 KB/CU/step from L2 (~1900 cyc at ~135 B/cyc/CU) -- the invariant
// 1600-1900 cyc/step bottleneck across all previous rounds. Registers are the
// only storage with enough bandwidth for W; the pin forces residency.
__global__ __launch_bounds__(512, 2)
void esn_scan_kernel(const float* __restrict__ x,
                     const float* __restrict__ W_in,
                     const float* __restrict__ W_res,
                     float* __restrict__ out) {
    __shared__ float h[2][HBUF];   // double-buffered state, padded

    const int tid  = threadIdx.x;
    const int b    = blockIdx.x;
    const int lane = tid & 63;
    const int wid  = tid >> 6;     // 0..7
    const int sub  = lane & 15;    // k-chunk selector
    const int g    = lane >> 4;    // 0..3 group within wave
    const int a    = lane & 7;     // output index this lane finalizes

    const int rbase = 32 * wid + 8 * g;   // group's first output
    const int ract  = rbase + a;          // output this lane writes (if sub<8)

    // Register-resident W slice as packed pairs:
    // w2[o][m] = { W_res[sub*16+2m][rbase+o], W_res[sub*16+2m+1][rbase+o] }
    f32x2 w2[8][8];
    #pragma unroll
    for (int o = 0; o < 8; ++o)
        #pragma unroll
        for (int m = 0; m < 8; ++m) {
            f32x2 p;
            p.x = W_res[(sub * 16 + 2 * m)     * RES + rbase + o];
            p.y = W_res[(sub * 16 + 2 * m + 1) * RES + rbase + o];
            w2[o][m] = p;
            // Pin: force VGPR residency, forbid remat of the global loads.
            asm volatile("" : "+v"(w2[o][m]));
        }

    float win[CIN];
    #pragma unroll
    for (int c = 0; c < CIN; ++c) {
        win[c] = W_in[c * RES + ract];
        asm volatile("" : "+v"(win[c]));
    }

    if (tid < HBUF) h[0][tid] = 0.0f;
    __syncthreads();

    const float* xb = x + (size_t)b * SEQ_T * CIN;
    float*       ob = out + (size_t)b * SEQ_T * RES + ract;

    const float4* hr0 = (const float4*)&h[0][sub * CSTRIDE];
    const float4* hr1 = (const float4*)&h[1][sub * CSTRIDE];
    const int wslot = ((ract >> 4) * CSTRIDE) + (ract & 15);
    float* hw0 = &h[0][wslot];
    float* hw1 = &h[1][wslot];
    const bool writer = (sub < 8);
    const bool p0 = (lane & 1) != 0;
    const bool p1 = (lane & 2) != 0;
    const bool p2 = (lane & 4) != 0;

    // x prefetch buffers (uniform -> scalarized)
    float xA[CIN], xB[CIN];
    #pragma unroll
    for (int c = 0; c < CIN; ++c) xA[c] = xb[c];
    xb += CIN;

#define ESN_STEP(HRD, HWR, XC, XN, PREF)                                \
    {                                                                   \
        float4 hv0 = (HRD)[0], hv1 = (HRD)[1], hv2 = (HRD)[2], hv3 = (HRD)[3]; \
        if (PREF) {                                                     \
            _Pragma("unroll")                                           \
            for (int c = 0; c < CIN; ++c) (XN)[c] = xb[c];              \
            xb += CIN;                                                  \
        }                                                               \
        f32x2 hp[8];                                                    \
        hp[0].x = hv0.x; hp[0].y = hv0.y; hp[1].x = hv0.z; hp[1].y = hv0.w; \
        hp[2].x = hv1.x; hp[2].y = hv1.y; hp[3].x = hv1.z; hp[3].y = hv1.w; \
        hp[4].x = hv2.x; hp[4].y = hv2.y; hp[5].x = hv2.z; hp[5].y = hv2.w; \
        hp[6].x = hv3.x; hp[6].y = hv3.y; hp[7].x = hv3.z; hp[7].y = hv3.w; \
        float s0, s1, s2, s3, s4, s5, s6, s7;                           \
        {                                                               \
            f32x2 acc[8];                                               \
            _Pragma("unroll")                                           \
            for (int o = 0; o < 8; ++o) {                               \
                f32x2 t = {0.f, 0.f};                                   \
                _Pragma("unroll")                                       \
                for (int m = 0; m < 8; ++m) t = pk_fma(hp[m], w2[o][m], t); \
                acc[o] = t;                                             \
            }                                                           \
            s0 = acc[0].x + acc[0].y; s1 = acc[1].x + acc[1].y;         \
            s2 = acc[2].x + acc[2].y; s3 = acc[3].x + acc[3].y;         \
            s4 = acc[4].x + acc[4].y; s5 = acc[5].x + acc[5].y;         \
            s6 = acc[6].x + acc[6].y; s7 = acc[7].x + acc[7].y;         \
        }                                                               \
        /* 16-lane butterfly reduce; lane l ends with sum for a=l&7 */  \
        float t0 = dpp_xadd<0xB1>(p0 ? s1 : s0, p0 ? s0 : s1);          \
        float t1 = dpp_xadd<0xB1>(p0 ? s3 : s2, p0 ? s2 : s3);          \
        float t2 = dpp_xadd<0xB1>(p0 ? s5 : s4, p0 ? s4 : s5);          \
        float t3 = dpp_xadd<0xB1>(p0 ? s7 : s6, p0 ? s6 : s7);          \
        float u0 = dpp_xadd<0x4E>(p1 ? t1 : t0, p1 ? t0 : t1);          \
        float u1 = dpp_xadd<0x4E>(p1 ? t3 : t2, p1 ? t2 : t3);          \
        float v  = dpp_xadd<0x124>(p2 ? u1 : u0, p2 ? u0 : u1);         \
        float s  = dpp_add<0x128>(v);                                   \
        if (writer) {                                                   \
            _Pragma("unroll")                                           \
            for (int c = 0; c < CIN; ++c) s = fmaf((XC)[c], win[c], s); \
            float e  = __expf(2.0f * s);                                \
            float hn = 1.0f - 2.0f * __builtin_amdgcn_rcpf(e + 1.0f);   \
            *(HWR) = hn;                                                \
            *ob = hn;                                                   \
        }                                                               \
        ob += RES;                                                      \
        asm volatile("s_waitcnt lgkmcnt(0)" ::: "memory");              \
        __builtin_amdgcn_s_barrier();                                   \
        asm volatile("" ::: "memory");                                  \
    }

    // Main loop: unroll-2 over the double buffer; prefetch x one step ahead.
    for (int t = 0; t < SEQ_T - 2; t += 2) {
        ESN_STEP(hr0, hw1, xA, xB, 1);   // read h[0], write h[1]
        ESN_STEP(hr1, hw0, xB, xA, 1);   // read h[1], write h[0]
    }
    ESN_STEP(hr0, hw1, xA, xB, 1);       // t=510, prefetches x[511]
    ESN_STEP(hr1, hw0, xB, xA, 0);       // t=511, no prefetch
#undef ESN_STEP
}

extern "C" void kernel_launch(void* const* d_in, const int* in_sizes, int n_in,
                              void* d_out, int out_size, void* d_ws, size_t ws_size,
                              hipStream_t stream) {
    const float* x     = (const float*)d_in[0];
    const float* W_in  = (const float*)d_in[1];
    const float* W_res = (const float*)d_in[2];
    float*       out   = (float*)d_out;

    esn_scan_kernel<<<BATCH, 512, 0, stream>>>(x, W_in, W_res, out);
}